// Round 4
// baseline (1685.597 us; speedup 1.0000x reference)
//
#include <hip/hip_runtime.h>

namespace {
constexpr int Tn = 4096;
constexpr int Kn = 64;
constexpr int BATCH = 128;
constexpr int START_TAG = 62;
constexpr int STOP_TAG = 63;
constexpr float NEGV = -10000.0f;
constexpr int CH = 64;            // backtrace chunk length
constexpr int NCH = Tn / CH;      // 64 chunks
constexpr int GL = 8;             // feats burst length
constexpr int NG = Tn / GL;       // 512 groups
constexpr int RS = 128;           // delta/max ring slots (pow2)
constexpr int RB = 128;           // backpointer ring slots (pow2)
constexpr int CW = 16;            // consumer chunk width

typedef float f32x4 __attribute__((ext_vector_type(4)));

__device__ __forceinline__ float rfl(float x) {
    return __uint_as_float(__builtin_amdgcn_readfirstlane(__float_as_uint(x)));
}
__device__ __forceinline__ void cfence() { __asm__ volatile("" ::: "memory"); }
__device__ __forceinline__ void lgkm0() { __asm__ volatile("s_waitcnt lgkmcnt(0)" ::: "memory"); }
__device__ __forceinline__ int imin(int a, int b) { return a < b ? a : b; }
__device__ __forceinline__ float m3(float a, float b, float c) {
    return fmaxf(fmaxf(a, b), c);   // clang fuses to v_max3_f32
}

// pinned pipeline primitives ------------------------------------------------
// top-of-step: wait all DS (prev step's gather) then fence the scheduler so
// the compiler cannot hoist the consuming VALU ops above the wait (rule #18).
#define DS_WAIT() do {                                                         \
        asm volatile("s_waitcnt lgkmcnt(0)" ::: "memory");                     \
        __builtin_amdgcn_sched_barrier(0);                                     \
    } while (0)

#define DS_PUT(WO, VAL)                                                        \
    asm volatile("ds_write_b32 %0, %1" :: "v"(WO), "v"(VAL) : "memory")

// 16 back-to-back broadcast ds_read_b128 into pinned registers (no wait here)
#define DS_GATHER(RO)                                                          \
    asm volatile(                                                              \
        "ds_read_b128 %0, %16 offset:0\n\t"                                    \
        "ds_read_b128 %1, %16 offset:16\n\t"                                   \
        "ds_read_b128 %2, %16 offset:32\n\t"                                   \
        "ds_read_b128 %3, %16 offset:48\n\t"                                   \
        "ds_read_b128 %4, %16 offset:64\n\t"                                   \
        "ds_read_b128 %5, %16 offset:80\n\t"                                   \
        "ds_read_b128 %6, %16 offset:96\n\t"                                   \
        "ds_read_b128 %7, %16 offset:112\n\t"                                  \
        "ds_read_b128 %8, %16 offset:128\n\t"                                  \
        "ds_read_b128 %9, %16 offset:144\n\t"                                  \
        "ds_read_b128 %10, %16 offset:160\n\t"                                 \
        "ds_read_b128 %11, %16 offset:176\n\t"                                 \
        "ds_read_b128 %12, %16 offset:192\n\t"                                 \
        "ds_read_b128 %13, %16 offset:208\n\t"                                 \
        "ds_read_b128 %14, %16 offset:224\n\t"                                 \
        "ds_read_b128 %15, %16 offset:240"                                     \
        : "=&v"(g0), "=&v"(g1), "=&v"(g2), "=&v"(g3),                          \
          "=&v"(g4), "=&v"(g5), "=&v"(g6), "=&v"(g7),                          \
          "=&v"(g8), "=&v"(g9), "=&v"(g10), "=&v"(g11),                        \
          "=&v"(g12), "=&v"(g13), "=&v"(g14), "=&v"(g15)                       \
        : "v"(RO))

__global__ __launch_bounds__(256, 1)
void crf_kernel(const float* __restrict__ feats,   // [B,T,K]
                const int* __restrict__ tags,      // [B,T]
                const float* __restrict__ trans,   // [K,K] trans[next,prev]
                float* __restrict__ out,           // [B] nll | [B] path_score | [B,T] path
                unsigned int* __restrict__ bp32)   // [B,T/4,K] packed backpointers
{
    const int tid = threadIdx.x;
    const int lane = tid & 63;
    const int wid = tid >> 6;
    const int b = blockIdx.x & (BATCH - 1);
    const size_t fb = (size_t)b * Tn * Kn;

    __shared__ float gw[4];
    __shared__ __align__(16) float vbuf[Kn];            // fwd broadcast buffer
    __shared__ __align__(16) float ring_v[RS][Kn];      // vit: delta_t vectors (32KB)
    __shared__ float ring_m[RS][Kn];                    // vit: pre-feat max m_t (32KB)
    __shared__ unsigned char ring_bp[RB][Kn];           // vit: backpointer ring
    __shared__ unsigned char snap[NCH * Kn];
    __shared__ unsigned char echain[NCH];
    __shared__ int prog_a[Kn], prog_b[Kn], prog_c[Kn], prog_d[Kn];
    __shared__ int done_b[Kn], done_c[Kn];

    const unsigned lane4 = (unsigned)lane * 4u;

    if (blockIdx.x < BATCH) {
        // ================= forward log-partition + gold -> nll =================
        float gold = 0.0f;
        {
            const int t0 = tid * (Tn / 256);
            int prev = (tid == 0) ? START_TAG : tags[(size_t)b * Tn + t0 - 1];
            for (int k = 0; k < Tn / 256; ++k) {
                const int t = t0 + k;
                const int tg = tags[(size_t)b * Tn + t];
                gold += trans[tg * Kn + prev] + feats[fb + (size_t)t * Kn + tg];
                prev = tg;
            }
            if (tid == 255) gold += trans[STOP_TAG * Kn + prev];
            #pragma unroll
            for (int off = 32; off; off >>= 1) gold += __shfl_down(gold, off);
            if (lane == 0) gw[wid] = gold;
        }
        __syncthreads();
        if (wid != 0) return;   // single wave owns the recurrence

        float ES[Kn];           // lane j: exp(trans[j, 0..63])
        #pragma unroll
        for (int q = 0; q < Kn / 4; ++q) {
            const float4 t4 = ((const float4*)(trans + lane * Kn))[q];
            ES[4*q+0] = __expf(t4.x); ES[4*q+1] = __expf(t4.y);
            ES[4*q+2] = __expf(t4.z); ES[4*q+3] = __expf(t4.w);
        }
        float v = (lane == START_TAG) ? 1.0f : 0.0f;  // exp-domain one-hot
        float O = 0.0f;
        float fc[GL], fn[GL], Fc[GL];
        #pragma unroll
        for (int k = 0; k < GL; ++k) fc[k] = feats[fb + (size_t)k * Kn + lane];

        const unsigned vb_ro = (unsigned)(size_t)&vbuf[0];   // LDS byte offset
        const unsigned vb_wo = vb_ro + lane4;

        f32x4 g0, g1, g2, g3, g4, g5, g6, g7, g8, g9, g10, g11, g12, g13, g14, g15;
        DS_PUT(vb_wo, v);
        DS_GATHER(vb_ro);

#define FMAQ(Q, A, B2, C, D) ({                                                \
        float s0_ = 0.f, s1_ = 0.f, s2_ = 0.f, s3_ = 0.f;                      \
        s0_ = fmaf(ES[16*(Q)+0],  (A)[0],  s0_); s1_ = fmaf(ES[16*(Q)+1],  (A)[1],  s1_); \
        s2_ = fmaf(ES[16*(Q)+2],  (A)[2],  s2_); s3_ = fmaf(ES[16*(Q)+3],  (A)[3],  s3_); \
        s0_ = fmaf(ES[16*(Q)+4],  (B2)[0], s0_); s1_ = fmaf(ES[16*(Q)+5],  (B2)[1], s1_); \
        s2_ = fmaf(ES[16*(Q)+6],  (B2)[2], s2_); s3_ = fmaf(ES[16*(Q)+7],  (B2)[3], s3_); \
        s0_ = fmaf(ES[16*(Q)+8],  (C)[0],  s0_); s1_ = fmaf(ES[16*(Q)+9],  (C)[1],  s1_); \
        s2_ = fmaf(ES[16*(Q)+10], (C)[2],  s2_); s3_ = fmaf(ES[16*(Q)+11], (C)[3],  s3_); \
        s0_ = fmaf(ES[16*(Q)+12], (D)[0],  s0_); s1_ = fmaf(ES[16*(Q)+13], (D)[1],  s1_); \
        s2_ = fmaf(ES[16*(Q)+14], (D)[2],  s2_); s3_ = fmaf(ES[16*(Q)+15], (D)[3],  s3_); \
        (s0_ + s1_) + (s2_ + s3_); })

#define FWD_STEP(K) do {                                                       \
        DS_WAIT();                                                             \
        const float w0_ = FMAQ(0, g0,  g1,  g2,  g3);                          \
        const float w1_ = FMAQ(1, g4,  g5,  g6,  g7);                          \
        const float w2_ = FMAQ(2, g8,  g9,  g10, g11);                         \
        const float w3_ = FMAQ(3, g12, g13, g14, g15);                         \
        const float w_ = ((w0_ + w1_) + (w2_ + w3_)) * Fc[K];                  \
        const float wz_ = rfl(w_);                                             \
        v = w_ * __builtin_amdgcn_rcpf(wz_);                                   \
        DS_PUT(vb_wo, v);                                                      \
        DS_GATHER(vb_ro);             /* in flight until next DS_WAIT */       \
        O += __logf(wz_);             /* off-chain, fills the read shadow */   \
    } while (0)

        for (int g = 0; g < NG; ++g) {
            if (g + 1 < NG) {
                const size_t base = fb + (size_t)(g + 1) * GL * Kn + lane;
                #pragma unroll
                for (int k = 0; k < GL; ++k) fn[k] = feats[base + (size_t)k * Kn];
            }
            #pragma unroll
            for (int k = 0; k < GL; ++k) Fc[k] = __expf(fc[k]);
            #pragma unroll
            for (int k = 0; k < GL; ++k) FWD_STEP(k);
            #pragma unroll
            for (int k = 0; k < GL; ++k) fc[k] = fn[k];
        }
#undef FWD_STEP
        {
            const float a = O + __logf(v);
            const float x = a + trans[STOP_TAG * Kn + lane];
            float mx = x;
            #pragma unroll
            for (int off = 32; off; off >>= 1) mx = fmaxf(mx, __shfl_xor(mx, off));
            float se = __expf(x - mx);
            #pragma unroll
            for (int off = 32; off; off >>= 1) se += __shfl_xor(se, off);
            if (lane == 0)
                out[b] = (mx + __logf(se)) - (((gw[0] + gw[1]) + (gw[2] + gw[3])));
        }
        return;
    }

    // ========= Viterbi: A(value chain) | B/C(argmax, 16-step chunks) | D(survivor) =========
    volatile int* pa = (volatile int*)prog_a;
    volatile int* pb = (volatile int*)prog_b;
    volatile int* pc = (volatile int*)prog_c;
    volatile int* pd = (volatile int*)prog_d;
    volatile int* db = (volatile int*)done_b;
    volatile int* dc = (volatile int*)done_c;
    if (wid == 0) { pa[lane] = 0; pb[lane] = 0; }
    if (wid == 1) { pc[lane] = 0; pd[lane] = 0; }
    if (wid == 2) { db[lane] = 0; dc[lane] = 0; }
    __syncthreads();   // the only barrier in the vit block

    float trS[Kn];     // lane j: trans[j, 0..63]
    #pragma unroll
    for (int q = 0; q < Kn / 4; ++q) {
        const float4 t4 = ((const float4*)(trans + lane * Kn))[q];
        trS[4*q+0] = t4.x; trS[4*q+1] = t4.y; trS[4*q+2] = t4.z; trS[4*q+3] = t4.w;
    }

    if (wid == 0) {
        // ---- A: delta value chain (critical path), asm-pinned pipeline ----
        float v = (lane == START_TAG) ? 0.0f : NEGV;
        float fc[GL], fn[GL];
        #pragma unroll
        for (int k = 0; k < GL; ++k) fc[k] = feats[fb + (size_t)k * Kn + lane];

        const unsigned ring_o = (unsigned)(size_t)&ring_v[0][0];
        f32x4 g0, g1, g2, g3, g4, g5, g6, g7, g8, g9, g10, g11, g12, g13, g14, g15;
        DS_PUT(ring_o + lane4, v);      // slot 0 = init delta
        DS_GATHER(ring_o);

#define VQ(Q, DV) ({                                                           \
        const float sx_ = (DV)[0] + trS[4*(Q)+0];                              \
        const float sy_ = (DV)[1] + trS[4*(Q)+1];                              \
        const float sz_ = (DV)[2] + trS[4*(Q)+2];                              \
        const float sw_ = (DV)[3] + trS[4*(Q)+3];                              \
        fmaxf(m3(sx_, sy_, sz_), sw_); })

#define VIT_STEP(K) do {                                                       \
        const int t_ = g * GL + (K);                                           \
        DS_WAIT();                                                             \
        const float q0_  = VQ(0,  g0),  q1_  = VQ(1,  g1);                     \
        const float q2_  = VQ(2,  g2),  q3_  = VQ(3,  g3);                     \
        const float q4_  = VQ(4,  g4),  q5_  = VQ(5,  g5);                     \
        const float q6_  = VQ(6,  g6),  q7_  = VQ(7,  g7);                     \
        const float q8_  = VQ(8,  g8),  q9_  = VQ(9,  g9);                     \
        const float q10_ = VQ(10, g10), q11_ = VQ(11, g11);                    \
        const float q12_ = VQ(12, g12), q13_ = VQ(13, g13);                    \
        const float q14_ = VQ(14, g14), q15_ = VQ(15, g15);                    \
        const float r0_ = m3(q0_,  q1_,  q2_);                                 \
        const float r1_ = m3(q3_,  q4_,  q5_);                                 \
        const float r2_ = m3(q6_,  q7_,  q8_);                                 \
        const float r3_ = m3(q9_,  q10_, q11_);                                \
        const float r4_ = m3(q12_, q13_, q14_);                                \
        const float mm_ = fmaxf(m3(m3(r0_, r1_, r2_), r3_, r4_), q15_);        \
        v = mm_ + fc[K];                /* feat added after max, as in torch */ \
        const unsigned ro_ = ring_o + (((unsigned)(t_ + 1) & (RS - 1)) << 8);  \
        DS_PUT(ro_ + lane4, v);                                                \
        DS_GATHER(ro_);                 /* in flight until next DS_WAIT */     \
        ring_m[t_ & (RS - 1)][lane] = mm_;   /* in the read shadow */          \
    } while (0)

        for (int g = 0; g < NG; ++g) {
            if (g + 1 < NG) {
                const size_t base = fb + (size_t)(g + 1) * GL * Kn + lane;
                #pragma unroll
                for (int k = 0; k < GL; ++k) fn[k] = feats[base + (size_t)k * Kn];
            }
            // ring backpressure: once per 32 steps, margin 88 (never hit in steady state)
            if ((g & 3) == 0 && g >= 16) {
                const int t0 = g * GL;
                cfence();
                while (pb[lane] < t0 - 88 || pc[lane] < t0 - 88)
                    __builtin_amdgcn_s_sleep(1);
                cfence();
            }
            #pragma unroll
            for (int k = 0; k < GL; ++k) VIT_STEP(k);
            cfence();
            pa[lane] = g * GL + GL;     // one progress publish per 8 steps
            #pragma unroll
            for (int k = 0; k < GL; ++k) fc[k] = fn[k];
        }
#undef VIT_STEP
#undef VQ
        // ---- terminal argmax (first index on ties) ----
        const float term = v + trans[STOP_TAG * Kn + lane];
        float bv = term;
        int bi = lane;
        #pragma unroll
        for (int off = 32; off; off >>= 1) {
            const float ov = __shfl_xor(bv, off);
            const int oi = __shfl_xor(bi, off);
            if (ov > bv || (ov == bv && oi < bi)) { bv = ov; bi = oi; }
        }
        if (lane == 0) out[BATCH + b] = bv;
        while (pd[lane] < Tn) __builtin_amdgcn_s_sleep(1);
        cfence();
        if (lane == 0) {
            int e = bi;
            for (int c = NCH - 1; c >= 0; --c) {
                echain[c] = (unsigned char)e;
                e = snap[c * Kn + e];
            }
        }
        lgkm0();
        while (db[lane] == 0 || dc[lane] == 0) __builtin_amdgcn_s_sleep(1);
        cfence();
        // ---- within-chunk reconstruction: lane = chunk ----
        int tag = echain[lane];
        float* po = out + 2 * BATCH + (size_t)b * Tn;
        const size_t dwb = (size_t)b * (Tn / 4);
        for (int k = CH - 1; k >= 0; --k) {
            const int t = lane * CH + k;
            po[t] = (float)tag;
            tag = (int)((bp32[(dwb + (size_t)(t >> 2)) * Kn + tag] >> (8 * (t & 3))) & 63u);
        }
    } else if (wid == 1 || wid == 2) {
        // ---- B/C: argmax extraction, alternating 16-step chunks ----
        const int par = wid - 1;
        const size_t dwb = (size_t)b * (Tn / 4);
        volatile int* my = (par == 0) ? pb : pc;
        for (int c0 = par * CW; c0 < Tn; c0 += 2 * CW) {
            while (pa[lane] < c0 + CW) __builtin_amdgcn_s_sleep(1);
            cfence();
            if (c0 >= RB) {                       // ring_bp backpressure on D
                while (pd[lane] < c0 - (RB - CW)) __builtin_amdgcn_s_sleep(1);
                cfence();
            }
            for (int k4 = 0; k4 < CW; k4 += 4) {
                unsigned int bp4 = 0;
                #pragma unroll
                for (int k = 0; k < 4; ++k) {
                    const int t = c0 + k4 + k;
                    const float4* vp = (const float4*)ring_v[t & (RS - 1)];
                    const float m = ring_m[t & (RS - 1)][lane];   // A's exact max
                    int qi[16];
                    #pragma unroll
                    for (int q = 0; q < 16; ++q) {
                        const float4 dv = vp[q];
                        const float sx = dv.x + trS[4*q+0];   // bitwise == A's adds
                        const float sy = dv.y + trS[4*q+1];
                        const float sz = dv.z + trS[4*q+2];
                        const float sw = dv.w + trS[4*q+3];
                        const int ix = (sx == m) ? 4*q+0 : 255;
                        const int iy = (sy == m) ? 4*q+1 : 255;
                        const int iz = (sz == m) ? 4*q+2 : 255;
                        const int iw = (sw == m) ? 4*q+3 : 255;
                        qi[q] = imin(imin(ix, iy), imin(iz, iw));
                    }
                    int i8[8];
                    #pragma unroll
                    for (int q = 0; q < 8; ++q) i8[q] = imin(qi[2*q], qi[2*q+1]);
                    const int idx = imin(imin(imin(i8[0], i8[1]), imin(i8[2], i8[3])),
                                         imin(imin(i8[4], i8[5]), imin(i8[6], i8[7])));
                    ring_bp[t & (RB - 1)][lane] = (unsigned char)idx;
                    bp4 |= (unsigned int)idx << (8 * k);
                }
                bp32[(dwb + (size_t)((c0 + k4) >> 2)) * Kn + lane] = bp4;
            }
            cfence();
            my[lane] = c0 + CW;   // in-order DS: ring_bp writes visible first
        }
        __asm__ volatile("s_waitcnt vmcnt(0)" ::: "memory");
        if (par == 0) db[lane] = 1; else dc[lane] = 1;
    } else {
        // ---- D: survivor shuffle chain, 16-step chunks ----
        int h = lane;
        for (int c0 = 0; c0 < Tn; c0 += CW) {
            volatile int* pp = ((c0 >> 4) & 1) ? pc : pb;
            while (pp[lane] < c0 + CW) __builtin_amdgcn_s_sleep(1);
            cfence();
            int bpv[CW];
            #pragma unroll
            for (int k = 0; k < CW; ++k)
                bpv[k] = (int)ring_bp[(c0 + k) & (RB - 1)][lane];
            #pragma unroll
            for (int k = 0; k < CW; ++k) h = __shfl(h, bpv[k]);
            if (((c0 >> 4) & 3) == 3) {
                snap[(c0 >> 6) * Kn + lane] = (unsigned char)h;
                h = lane;
            }
            cfence();
            pd[lane] = c0 + CW;
        }
    }
#undef FMAQ
}
} // namespace

extern "C" void kernel_launch(void* const* d_in, const int* in_sizes, int n_in,
                              void* d_out, int out_size, void* d_ws, size_t ws_size,
                              hipStream_t stream)
{
    const float* feats = (const float*)d_in[0];
    const int* tags   = (const int*)d_in[1];
    const float* trans = (const float*)d_in[2];
    float* out = (float*)d_out;
    unsigned int* bp = (unsigned int*)d_ws;  // needs 128*1024*64*4 B = 32 MB
    hipLaunchKernelGGL(crf_kernel, dim3(2 * BATCH), dim3(256), 0, stream,
                       feats, tags, trans, out, bp);
}

// Round 5
// 1667.664 us; speedup vs baseline: 1.0108x; 1.0108x over previous
//
#include <hip/hip_runtime.h>

namespace {
constexpr int Tn = 4096;
constexpr int Kn = 64;
constexpr int BATCH = 128;
constexpr int START_TAG = 62;
constexpr int STOP_TAG = 63;
constexpr float NEGV = -10000.0f;
constexpr int CH = 64;            // backtrace chunk length
constexpr int NCH = Tn / CH;      // 64 chunks
constexpr int GL = 8;             // feats burst length
constexpr int NG = Tn / GL;       // 512 groups
constexpr int RS = 128;           // delta/max ring slots (pow2)
constexpr int RB = 128;           // backpointer ring slots (pow2)
constexpr int CW = 16;            // consumer chunk width

typedef float f32x4 __attribute__((ext_vector_type(4)));

__device__ __forceinline__ float rfl(float x) {
    return __uint_as_float(__builtin_amdgcn_readfirstlane(__float_as_uint(x)));
}
__device__ __forceinline__ void cfence() { __asm__ volatile("" ::: "memory"); }
__device__ __forceinline__ void lgkm0() { __asm__ volatile("s_waitcnt lgkmcnt(0)" ::: "memory"); }
__device__ __forceinline__ int imin(int a, int b) { return a < b ? a : b; }
__device__ __forceinline__ float m3(float a, float b, float c) {
    return fmaxf(fmaxf(a, b), c);   // clang fuses to v_max3_f32
}

// staged waits: DS ops retire in order; constant N guarantees the oldest
// (outstanding-N) ops completed. sched_barrier stops hoisting (rule #18).
#define DSW(N) do {                                                            \
        asm volatile("s_waitcnt lgkmcnt(" #N ")" ::: "memory");                \
        __builtin_amdgcn_sched_barrier(0);                                     \
    } while (0)

#define DS_PUT(WO, VAL)                                                        \
    asm volatile("ds_write_b32 %0, %1" :: "v"(WO), "v"(VAL) : "memory")

// 16 back-to-back broadcast ds_read_b128 into pinned registers (no wait here)
#define DS_GATHER(RO)                                                          \
    asm volatile(                                                              \
        "ds_read_b128 %0, %16 offset:0\n\t"                                    \
        "ds_read_b128 %1, %16 offset:16\n\t"                                   \
        "ds_read_b128 %2, %16 offset:32\n\t"                                   \
        "ds_read_b128 %3, %16 offset:48\n\t"                                   \
        "ds_read_b128 %4, %16 offset:64\n\t"                                   \
        "ds_read_b128 %5, %16 offset:80\n\t"                                   \
        "ds_read_b128 %6, %16 offset:96\n\t"                                   \
        "ds_read_b128 %7, %16 offset:112\n\t"                                  \
        "ds_read_b128 %8, %16 offset:128\n\t"                                  \
        "ds_read_b128 %9, %16 offset:144\n\t"                                  \
        "ds_read_b128 %10, %16 offset:160\n\t"                                 \
        "ds_read_b128 %11, %16 offset:176\n\t"                                 \
        "ds_read_b128 %12, %16 offset:192\n\t"                                 \
        "ds_read_b128 %13, %16 offset:208\n\t"                                 \
        "ds_read_b128 %14, %16 offset:224\n\t"                                 \
        "ds_read_b128 %15, %16 offset:240"                                     \
        : "=&v"(g0), "=&v"(g1), "=&v"(g2), "=&v"(g3),                          \
          "=&v"(g4), "=&v"(g5), "=&v"(g6), "=&v"(g7),                          \
          "=&v"(g8), "=&v"(g9), "=&v"(g10), "=&v"(g11),                        \
          "=&v"(g12), "=&v"(g13), "=&v"(g14), "=&v"(g15)                       \
        : "v"(RO))

__global__ __launch_bounds__(256, 1)
void crf_kernel(const float* __restrict__ feats,   // [B,T,K]
                const int* __restrict__ tags,      // [B,T]
                const float* __restrict__ trans,   // [K,K] trans[next,prev]
                float* __restrict__ out,           // [B] nll | [B] path_score | [B,T] path
                unsigned int* __restrict__ bp32)   // [B,T/4,K] packed backpointers
{
    const int tid = threadIdx.x;
    const int lane = tid & 63;
    const int wid = tid >> 6;
    const int b = blockIdx.x & (BATCH - 1);
    const size_t fb = (size_t)b * Tn * Kn;

    __shared__ float gw[4];
    __shared__ __align__(16) float vbuf[Kn];            // fwd broadcast buffer
    __shared__ __align__(16) float ring_v[RS][Kn];      // vit: delta_t vectors (32KB)
    __shared__ __align__(16) float ring_m[RS][Kn];      // vit: pre-feat max m_t (32KB)
    __shared__ unsigned char ring_bp[RB][Kn];           // vit: backpointer ring
    __shared__ unsigned char snap[NCH * Kn];
    __shared__ unsigned char echain[NCH];
    __shared__ int prog_a[Kn], prog_b[Kn], prog_c[Kn], prog_d[Kn];
    __shared__ int done_b[Kn], done_c[Kn];

    const unsigned lane4 = (unsigned)lane * 4u;

    if (blockIdx.x < BATCH) {
        // ================= forward log-partition + gold -> nll =================
        float gold = 0.0f;
        {
            const int t0 = tid * (Tn / 256);
            int prev = (tid == 0) ? START_TAG : tags[(size_t)b * Tn + t0 - 1];
            for (int k = 0; k < Tn / 256; ++k) {
                const int t = t0 + k;
                const int tg = tags[(size_t)b * Tn + t];
                gold += trans[tg * Kn + prev] + feats[fb + (size_t)t * Kn + tg];
                prev = tg;
            }
            if (tid == 255) gold += trans[STOP_TAG * Kn + prev];
            #pragma unroll
            for (int off = 32; off; off >>= 1) gold += __shfl_down(gold, off);
            if (lane == 0) gw[wid] = gold;
        }
        __syncthreads();
        if (wid != 0) return;   // single wave owns the recurrence

        float ES[Kn];           // lane j: exp(trans[j, 0..63])
        #pragma unroll
        for (int q = 0; q < Kn / 4; ++q) {
            const float4 t4 = ((const float4*)(trans + lane * Kn))[q];
            ES[4*q+0] = __expf(t4.x); ES[4*q+1] = __expf(t4.y);
            ES[4*q+2] = __expf(t4.z); ES[4*q+3] = __expf(t4.w);
        }
        float v = (lane == START_TAG) ? 1.0f : 0.0f;  // exp-domain one-hot
        float O = 0.0f;
        float fc[GL], fn[GL], Fc[GL];
        #pragma unroll
        for (int k = 0; k < GL; ++k) fc[k] = feats[fb + (size_t)k * Kn + lane];

        const unsigned vb_ro = (unsigned)(size_t)&vbuf[0];   // LDS byte offset
        const unsigned vb_wo = vb_ro + lane4;

        f32x4 g0, g1, g2, g3, g4, g5, g6, g7, g8, g9, g10, g11, g12, g13, g14, g15;
        DS_PUT(vb_wo, v);
        DS_GATHER(vb_ro);

#define FMAQ(Q, A, B2, C, D) ({                                                \
        float s0_ = 0.f, s1_ = 0.f, s2_ = 0.f, s3_ = 0.f;                      \
        s0_ = fmaf(ES[16*(Q)+0],  (A)[0],  s0_); s1_ = fmaf(ES[16*(Q)+1],  (A)[1],  s1_); \
        s2_ = fmaf(ES[16*(Q)+2],  (A)[2],  s2_); s3_ = fmaf(ES[16*(Q)+3],  (A)[3],  s3_); \
        s0_ = fmaf(ES[16*(Q)+4],  (B2)[0], s0_); s1_ = fmaf(ES[16*(Q)+5],  (B2)[1], s1_); \
        s2_ = fmaf(ES[16*(Q)+6],  (B2)[2], s2_); s3_ = fmaf(ES[16*(Q)+7],  (B2)[3], s3_); \
        s0_ = fmaf(ES[16*(Q)+8],  (C)[0],  s0_); s1_ = fmaf(ES[16*(Q)+9],  (C)[1],  s1_); \
        s2_ = fmaf(ES[16*(Q)+10], (C)[2],  s2_); s3_ = fmaf(ES[16*(Q)+11], (C)[3],  s3_); \
        s0_ = fmaf(ES[16*(Q)+12], (D)[0],  s0_); s1_ = fmaf(ES[16*(Q)+13], (D)[1],  s1_); \
        s2_ = fmaf(ES[16*(Q)+14], (D)[2],  s2_); s3_ = fmaf(ES[16*(Q)+15], (D)[3],  s3_); \
        (s0_ + s1_) + (s2_ + s3_); })

// queue at step top: {PUT, R0..R15} (17). lgkmcnt 12/8/4/0 -> R0-3/R4-7/R8-11/all done.
#define FWD_STEP(K) do {                                                       \
        DSW(12);                                                               \
        const float w0_ = FMAQ(0, g0,  g1,  g2,  g3);                          \
        DSW(8);                                                                \
        const float w1_ = FMAQ(1, g4,  g5,  g6,  g7);                          \
        DSW(4);                                                                \
        const float w2_ = FMAQ(2, g8,  g9,  g10, g11);                         \
        DSW(0);                                                                \
        const float w3_ = FMAQ(3, g12, g13, g14, g15);                         \
        const float w_ = ((w0_ + w1_) + (w2_ + w3_)) * Fc[K];                  \
        const float wz_ = rfl(w_);                                             \
        v = w_ * __builtin_amdgcn_rcpf(wz_);                                   \
        DS_PUT(vb_wo, v);                                                      \
        DS_GATHER(vb_ro);             /* in flight until next step's waits */  \
        O += __logf(wz_);             /* off-chain, fills the read shadow */   \
    } while (0)

        for (int g = 0; g < NG; ++g) {
            if (g + 1 < NG) {
                const size_t base = fb + (size_t)(g + 1) * GL * Kn + lane;
                #pragma unroll
                for (int k = 0; k < GL; ++k) fn[k] = feats[base + (size_t)k * Kn];
            }
            #pragma unroll
            for (int k = 0; k < GL; ++k) Fc[k] = __expf(fc[k]);
            #pragma unroll
            for (int k = 0; k < GL; ++k) FWD_STEP(k);
            #pragma unroll
            for (int k = 0; k < GL; ++k) fc[k] = fn[k];
        }
#undef FWD_STEP
        {
            const float a = O + __logf(v);
            const float x = a + trans[STOP_TAG * Kn + lane];
            float mx = x;
            #pragma unroll
            for (int off = 32; off; off >>= 1) mx = fmaxf(mx, __shfl_xor(mx, off));
            float se = __expf(x - mx);
            #pragma unroll
            for (int off = 32; off; off >>= 1) se += __shfl_xor(se, off);
            if (lane == 0)
                out[b] = (mx + __logf(se)) - (((gw[0] + gw[1]) + (gw[2] + gw[3])));
        }
        return;
    }

    // ========= Viterbi: A(value chain) | B/C(argmax, 16-step chunks) | D(survivor) =========
    volatile int* pa = (volatile int*)prog_a;
    volatile int* pb = (volatile int*)prog_b;
    volatile int* pc = (volatile int*)prog_c;
    volatile int* pd = (volatile int*)prog_d;
    volatile int* db = (volatile int*)done_b;
    volatile int* dc = (volatile int*)done_c;
    if (wid == 0) { pa[lane] = 0; pb[lane] = 0; }
    if (wid == 1) { pc[lane] = 0; pd[lane] = 0; }
    if (wid == 2) { db[lane] = 0; dc[lane] = 0; }
    __syncthreads();   // the only barrier in the vit block

    float trS[Kn];     // lane j: trans[j, 0..63]
    #pragma unroll
    for (int q = 0; q < Kn / 4; ++q) {
        const float4 t4 = ((const float4*)(trans + lane * Kn))[q];
        trS[4*q+0] = t4.x; trS[4*q+1] = t4.y; trS[4*q+2] = t4.z; trS[4*q+3] = t4.w;
    }

    if (wid == 0) {
        // ---- A: delta value chain (critical path), staged-wait pipeline ----
        float v = (lane == START_TAG) ? 0.0f : NEGV;
        float fc[GL], fn[GL];
        #pragma unroll
        for (int k = 0; k < GL; ++k) fc[k] = feats[fb + (size_t)k * Kn + lane];

        const unsigned ring_o = (unsigned)(size_t)&ring_v[0][0];
        const unsigned rm_o = (unsigned)(size_t)&ring_m[0][0];
        f32x4 g0, g1, g2, g3, g4, g5, g6, g7, g8, g9, g10, g11, g12, g13, g14, g15;
        DS_PUT(ring_o + lane4, v);      // slot 0 = init delta
        DS_GATHER(ring_o);

#define VQ(Q, DV) ({                                                           \
        const float sx_ = (DV)[0] + trS[4*(Q)+0];                              \
        const float sy_ = (DV)[1] + trS[4*(Q)+1];                              \
        const float sz_ = (DV)[2] + trS[4*(Q)+2];                              \
        const float sw_ = (DV)[3] + trS[4*(Q)+3];                              \
        fmaxf(m3(sx_, sy_, sz_), sw_); })

// queue at step top: {PUTv, PUTm, R0..R15} (18; first step 17). waits 12/8/4/0
// guarantee oldest 6/10/14/18 done -> R0-3 / R4-7 / R8-11 / all.
#define VIT_STEP(K) do {                                                       \
        const int t_ = g * GL + (K);                                           \
        DSW(12);                                                               \
        const float q0_  = VQ(0,  g0),  q1_  = VQ(1,  g1);                     \
        const float q2_  = VQ(2,  g2),  q3_  = VQ(3,  g3);                     \
        DSW(8);                                                                \
        const float q4_  = VQ(4,  g4),  q5_  = VQ(5,  g5);                     \
        const float q6_  = VQ(6,  g6),  q7_  = VQ(7,  g7);                     \
        DSW(4);                                                                \
        const float q8_  = VQ(8,  g8),  q9_  = VQ(9,  g9);                     \
        const float q10_ = VQ(10, g10), q11_ = VQ(11, g11);                    \
        DSW(0);                                                                \
        const float q12_ = VQ(12, g12), q13_ = VQ(13, g13);                    \
        const float q14_ = VQ(14, g14), q15_ = VQ(15, g15);                    \
        const float r0_ = m3(q0_,  q1_,  q2_);                                 \
        const float r1_ = m3(q3_,  q4_,  q5_);                                 \
        const float r2_ = m3(q6_,  q7_,  q8_);                                 \
        const float r3_ = m3(q9_,  q10_, q11_);                                \
        const float r4_ = m3(q12_, q13_, q14_);                                \
        const float mm_ = fmaxf(m3(m3(r0_, r1_, r2_), r3_, r4_), q15_);        \
        const unsigned mo_ = rm_o + (((unsigned)t_ & (RS - 1)) << 8) + lane4;  \
        DS_PUT(mo_, mm_);               /* publish max BEFORE gather */        \
        v = mm_ + fc[K];                /* feat added after max, as in torch */ \
        const unsigned ro_ = ring_o + (((unsigned)(t_ + 1) & (RS - 1)) << 8);  \
        DS_PUT(ro_ + lane4, v);                                                \
        DS_GATHER(ro_);                 /* in flight until next step's waits */ \
    } while (0)

        for (int g = 0; g < NG; ++g) {
            if (g + 1 < NG) {
                const size_t base = fb + (size_t)(g + 1) * GL * Kn + lane;
                #pragma unroll
                for (int k = 0; k < GL; ++k) fn[k] = feats[base + (size_t)k * Kn];
            }
            // ring backpressure: once per 32 steps, margin 88 (never hit in steady state)
            if ((g & 3) == 0 && g >= 16) {
                const int t0 = g * GL;
                cfence();
                while (pb[lane] < t0 - 88 || pc[lane] < t0 - 88)
                    __builtin_amdgcn_s_sleep(1);
                cfence();
            }
            #pragma unroll
            for (int k = 0; k < GL; ++k) VIT_STEP(k);
            cfence();
            pa[lane] = g * GL + GL;     // one progress publish per 8 steps
            #pragma unroll
            for (int k = 0; k < GL; ++k) fc[k] = fn[k];
        }
#undef VIT_STEP
#undef VQ
        // ---- terminal argmax (first index on ties) ----
        const float term = v + trans[STOP_TAG * Kn + lane];
        float bv = term;
        int bi = lane;
        #pragma unroll
        for (int off = 32; off; off >>= 1) {
            const float ov = __shfl_xor(bv, off);
            const int oi = __shfl_xor(bi, off);
            if (ov > bv || (ov == bv && oi < bi)) { bv = ov; bi = oi; }
        }
        if (lane == 0) out[BATCH + b] = bv;
        while (pd[lane] < Tn) __builtin_amdgcn_s_sleep(1);
        cfence();
        if (lane == 0) {
            int e = bi;
            for (int c = NCH - 1; c >= 0; --c) {
                echain[c] = (unsigned char)e;
                e = snap[c * Kn + e];
            }
        }
        lgkm0();
        while (db[lane] == 0 || dc[lane] == 0) __builtin_amdgcn_s_sleep(1);
        cfence();
        // ---- within-chunk reconstruction: lane = chunk ----
        int tag = echain[lane];
        float* po = out + 2 * BATCH + (size_t)b * Tn;
        const size_t dwb = (size_t)b * (Tn / 4);
        for (int k = CH - 1; k >= 0; --k) {
            const int t = lane * CH + k;
            po[t] = (float)tag;
            tag = (int)((bp32[(dwb + (size_t)(t >> 2)) * Kn + tag] >> (8 * (t & 3))) & 63u);
        }
    } else if (wid == 1 || wid == 2) {
        // ---- B/C: argmax extraction, alternating 16-step chunks ----
        const int par = wid - 1;
        const size_t dwb = (size_t)b * (Tn / 4);
        volatile int* my = (par == 0) ? pb : pc;
        for (int c0 = par * CW; c0 < Tn; c0 += 2 * CW) {
            while (pa[lane] < c0 + CW) __builtin_amdgcn_s_sleep(1);
            cfence();
            if (c0 >= RB) {                       // ring_bp backpressure on D
                while (pd[lane] < c0 - (RB - CW)) __builtin_amdgcn_s_sleep(1);
                cfence();
            }
            for (int k4 = 0; k4 < CW; k4 += 4) {
                unsigned int bp4 = 0;
                #pragma unroll
                for (int k = 0; k < 4; ++k) {
                    const int t = c0 + k4 + k;
                    const float4* vp = (const float4*)ring_v[t & (RS - 1)];
                    const float m = ring_m[t & (RS - 1)][lane];   // A's exact max
                    int qi[16];
                    #pragma unroll
                    for (int q = 0; q < 16; ++q) {
                        const float4 dv = vp[q];
                        const float sx = dv.x + trS[4*q+0];   // bitwise == A's adds
                        const float sy = dv.y + trS[4*q+1];
                        const float sz = dv.z + trS[4*q+2];
                        const float sw = dv.w + trS[4*q+3];
                        const int ix = (sx == m) ? 4*q+0 : 255;
                        const int iy = (sy == m) ? 4*q+1 : 255;
                        const int iz = (sz == m) ? 4*q+2 : 255;
                        const int iw = (sw == m) ? 4*q+3 : 255;
                        qi[q] = imin(imin(ix, iy), imin(iz, iw));
                    }
                    int i8[8];
                    #pragma unroll
                    for (int q = 0; q < 8; ++q) i8[q] = imin(qi[2*q], qi[2*q+1]);
                    const int idx = imin(imin(imin(i8[0], i8[1]), imin(i8[2], i8[3])),
                                         imin(imin(i8[4], i8[5]), imin(i8[6], i8[7])));
                    ring_bp[t & (RB - 1)][lane] = (unsigned char)idx;
                    bp4 |= (unsigned int)idx << (8 * k);
                }
                bp32[(dwb + (size_t)((c0 + k4) >> 2)) * Kn + lane] = bp4;
            }
            cfence();
            my[lane] = c0 + CW;   // in-order DS: ring_bp writes visible first
        }
        __asm__ volatile("s_waitcnt vmcnt(0)" ::: "memory");
        if (par == 0) db[lane] = 1; else dc[lane] = 1;
    } else {
        // ---- D: survivor chain via permutation-composition tree (depth 5) ----
        int h = lane;
        for (int c0 = 0; c0 < Tn; c0 += CW) {
            volatile int* pp = ((c0 >> 4) & 1) ? pc : pb;
            while (pp[lane] < c0 + CW) __builtin_amdgcn_s_sleep(1);
            cfence();
            int bpv[CW];
            #pragma unroll
            for (int k = 0; k < CW; ++k)
                bpv[k] = (int)ring_bp[(c0 + k) & (RB - 1)][lane];
            // C = bp0.bp1.....bp15 with (f.g)[i] = f[g[i]]; shfl(a,idx) = a.idx
            const int p0 = __shfl(bpv[0],  bpv[1]),  p1 = __shfl(bpv[2],  bpv[3]);
            const int p2 = __shfl(bpv[4],  bpv[5]),  p3 = __shfl(bpv[6],  bpv[7]);
            const int p4 = __shfl(bpv[8],  bpv[9]),  p5 = __shfl(bpv[10], bpv[11]);
            const int p6 = __shfl(bpv[12], bpv[13]), p7 = __shfl(bpv[14], bpv[15]);
            const int q0 = __shfl(p0, p1), q1 = __shfl(p2, p3);
            const int q2 = __shfl(p4, p5), q3 = __shfl(p6, p7);
            const int r0 = __shfl(q0, q1), r1 = __shfl(q2, q3);
            const int C = __shfl(r0, r1);
            h = __shfl(h, C);
            if (((c0 >> 4) & 3) == 3) {
                snap[(c0 >> 6) * Kn + lane] = (unsigned char)h;
                h = lane;
            }
            cfence();
            pd[lane] = c0 + CW;
        }
    }
#undef FMAQ
}
} // namespace

extern "C" void kernel_launch(void* const* d_in, const int* in_sizes, int n_in,
                              void* d_out, int out_size, void* d_ws, size_t ws_size,
                              hipStream_t stream)
{
    const float* feats = (const float*)d_in[0];
    const int* tags   = (const int*)d_in[1];
    const float* trans = (const float*)d_in[2];
    float* out = (float*)d_out;
    unsigned int* bp = (unsigned int*)d_ws;  // needs 128*1024*64*4 B = 32 MB
    hipLaunchKernelGGL(crf_kernel, dim3(2 * BATCH), dim3(256), 0, stream,
                       feats, tags, trans, out, bp);
}